// Round 2
// 890.925 us; speedup vs baseline: 1.0224x; 1.0224x over previous
//
#include <hip/hip_runtime.h>

typedef _Float16 half8 __attribute__((ext_vector_type(8)));
typedef _Float16 half4 __attribute__((ext_vector_type(4)));
typedef float f32x4 __attribute__((ext_vector_type(4)));

#define NTOK 196           // tokens per window (14*14)
#define NHEAD 12

__device__ __forceinline__ ushort f2h_u(float f) {
    _Float16 h = (_Float16)f;
    return __builtin_bit_cast(ushort, h);
}

// async 16B global->LDS. lds ptr must be wave-uniform base; HW adds lane*16.
__device__ __forceinline__ void gl_lds16(const ushort* g, ushort* l) {
    __builtin_amdgcn_global_load_lds((const __attribute__((address_space(1))) void*)g,
                                     (__attribute__((address_space(3))) void*)l,
                                     16, 0, 0);
}

// ---------------- kernel 1: gather x into window-token order, fp32 -> fp16 ----
__global__ __launch_bounds__(256) void cvt_x(const float* __restrict__ x,
                                             ushort* __restrict__ xb) {
    int idx = blockIdx.x * 256 + threadIdx.x;        // < 50176*192 exactly
    int t   = idx / 192;
    int c   = (idx - t * 192) * 4;
    int win = t / NTOK;
    int n   = t - win * NTOK;
    int b  = win >> 4, wh = (win >> 2) & 3, ww = win & 3;
    int r  = n / 14,  cc = n - r * 14;
    const float4 v = *(const float4*)(x + (((b * 56 + wh * 14 + r) * 56) + ww * 14 + cc) * 768 + c);
    ushort4 o = make_ushort4(f2h_u(v.x), f2h_u(v.y), f2h_u(v.z), f2h_u(v.w));
    *(ushort4*)(xb + t * 768 + c) = o;
}

// ---------------- kernel 2: weights fp32 -> fp16 -----------------------------
__global__ __launch_bounds__(256) void cvt_w(const float* __restrict__ qkv_w,
                                             const float* __restrict__ proj_w,
                                             ushort* __restrict__ wq,
                                             ushort* __restrict__ wp) {
    int idx = blockIdx.x * 256 + threadIdx.x;        // < 3072*192 exactly
    int row = idx / 192;
    int c   = (idx - row * 192) * 4;
    const float* src;
    ushort* dst;
    if (row < 2304) { src = qkv_w + row * 768 + c;          dst = wq + row * 768 + c; }
    else            { src = proj_w + (row - 2304) * 768 + c; dst = wp + (row - 2304) * 768 + c; }
    float4 v = *(const float4*)src;
    *(ushort4*)dst = make_ushort4(f2h_u(v.x), f2h_u(v.y), f2h_u(v.z), f2h_u(v.w));
}

// ============================================================================
// Shared 256x256xK(=768) 8-phase K-loop (T2 swizzle + T3/T4 counted vmcnt + T5)
// 8 waves (2M x 4N), BK=64, double-buffered 128 KiB LDS.
// LDS map (ushort idx): A: buf*16384 + half*8192 ; B: 32768 + same.
// Half = 128 rows x 64 k-halfs (128 B/row). Read swizzle byte ^= ((row&7)<<4),
// realized at write time by pre-swizzling the per-lane global source column
// (global_load_lds writes linearly: rule #21 both-sides-or-neither).
// vmcnt ledger (steady state): 2 issues/phase x 4 phases; vmcnt(6) at phase 4
// retires exactly through iter-T-phase-1 = all of tile T+1. Tail: T=NT-2
// drains vmcnt(0); T=NT-1 stages nothing.
// ============================================================================
__device__ __forceinline__ void kloop256(const ushort* __restrict__ Ab,
                                         const ushort* __restrict__ Bb,
                                         ushort* sh,
                                         f32x4 (&acc)[8][4]) {
    const int tid = threadIdx.x, wave = tid >> 6, lane = tid & 63;
    const int quad = lane >> 4, l16 = lane & 15;
    const int wm = wave >> 2, wn = wave & 3;
    const int sr = lane >> 3;                       // 0..7 row-in-chunk
    const int sc = ((lane & 7) ^ sr) * 8;           // pre-swizzled col (halfs)
    const int rd_xor = (l16 & 7) << 4;              // read-side swizzle (bytes)
    const int rowB0 = (wn & 1) * 64;
    half8 Ar[4][2], Br[2][2][2];

    // stage one 64-row quarter (8 waves x 1 gl_lds = 8 KB). ldsHalf = half base.
#define STAGE_Q(srcK, ldsHalf, q) \
    gl_lds16((srcK) + ((q) * 64 + wave * 8 + sr) * 768 + sc, \
             (ldsHalf) + (((q) & 1) * 64 + wave * 8) * 64)

#define LD_A(QM, aB) \
    _Pragma("unroll") for (int mi = 0; mi < 4; ++mi) \
    _Pragma("unroll") for (int kk = 0; kk < 2; ++kk) \
        Ar[mi][kk] = *(const half8*)((aB) + \
            (((((QM) * 64 + mi * 16 + l16) * 128) + kk * 64 + quad * 16) ^ rd_xor))

#define LD_B(QN, bB) \
    _Pragma("unroll") for (int nj = 0; nj < 2; ++nj) \
    _Pragma("unroll") for (int kk = 0; kk < 2; ++kk) \
        Br[QN][nj][kk] = *(const half8*)((bB) + \
            ((((rowB0 + (QN) * 32 + nj * 16 + l16) * 128) + kk * 64 + quad * 16) ^ rd_xor))

#define MFMA_Q(QM, QN) \
    _Pragma("unroll") for (int mi = 0; mi < 4; ++mi) \
    _Pragma("unroll") for (int nj = 0; nj < 2; ++nj) \
    _Pragma("unroll") for (int kk = 0; kk < 2; ++kk) \
        acc[(QM) * 4 + mi][(QN) * 2 + nj] = __builtin_amdgcn_mfma_f32_16x16x32_f16( \
            Ar[mi][kk], Br[QN][nj][kk], acc[(QM) * 4 + mi][(QN) * 2 + nj], 0, 0, 0)

#define PH_SYNC_PRE() do { \
    __builtin_amdgcn_s_barrier(); \
    asm volatile("s_waitcnt lgkmcnt(0)" ::: "memory"); \
    __builtin_amdgcn_sched_barrier(0); \
    __builtin_amdgcn_s_setprio(1); } while (0)

#define PH_SYNC_POST() do { \
    __builtin_amdgcn_s_setprio(0); \
    __builtin_amdgcn_sched_barrier(0); \
    __builtin_amdgcn_s_barrier(); } while (0)

    // ---- prologue: tile0 fully; tile1 A_q0,A_q2 + B_q0..3 (6 loads last) ----
    {
        ushort* a0 = sh;
        ushort* b0 = sh + 32768;
        #pragma unroll
        for (int q = 0; q < 4; ++q) STAGE_Q(Ab, a0 + (q >> 1) * 8192, q);
        #pragma unroll
        for (int q = 0; q < 4; ++q) STAGE_Q(Bb, b0 + (q >> 1) * 8192, q);
        ushort* a1 = sh + 16384;
        ushort* b1 = sh + 32768 + 16384;
        STAGE_Q(Ab + 64, a1, 0);
        STAGE_Q(Ab + 64, a1 + 8192, 2);
        #pragma unroll
        for (int q = 0; q < 4; ++q) STAGE_Q(Bb + 64, b1 + (q >> 1) * 8192, q);
        asm volatile("s_waitcnt vmcnt(6)" ::: "memory");   // tile0 complete
        __builtin_amdgcn_s_barrier();
    }

    const int NT = 12;                               // K = 768 / 64
    for (int T = 0; T < NT; ++T) {
        const int buf = T & 1;
        const char* aB = (const char*)(sh + buf * 16384 + wm * 8192);
        const char* bB = (const char*)(sh + 32768 + buf * 16384 + (wn >> 1) * 8192);
        ushort* aN = sh + (buf ^ 1) * 16384;         // tile T+1 A buffer
        ushort* aC = sh + buf * 16384;               // tile T+2 buffers (== cur)
        ushort* bC = sh + 32768 + buf * 16384;
        const bool p1 = (T + 1 < NT), p2 = (T + 2 < NT);

        // ---- phase 1: Q(0,0); issue A_q1,A_q3 of T+1 ----
        LD_A(0, aB); LD_B(0, bB);
        if (p1) { STAGE_Q(Ab + (T + 1) * 64, aN, 1);
                  STAGE_Q(Ab + (T + 1) * 64, aN + 8192, 3); }
        PH_SYNC_PRE(); MFMA_Q(0, 0); PH_SYNC_POST();

        // ---- phase 2: Q(0,1); issue A_q0,A_q2 of T+2 (regions read @ph1) ----
        LD_B(1, bB);
        if (p2) { STAGE_Q(Ab + (T + 2) * 64, aC, 0);
                  STAGE_Q(Ab + (T + 2) * 64, aC + 8192, 2); }
        PH_SYNC_PRE(); MFMA_Q(0, 1); PH_SYNC_POST();

        // ---- phase 3: Q(1,1); issue B_q0,B_q1 of T+2 (B read done @ph2) ----
        LD_A(1, aB);
        if (p2) { STAGE_Q(Bb + (T + 2) * 64, bC, 0);
                  STAGE_Q(Bb + (T + 2) * 64, bC, 1); }
        PH_SYNC_PRE(); MFMA_Q(1, 1); PH_SYNC_POST();

        // ---- phase 4: Q(1,0) on retained regs; issue B_q2,B_q3 of T+2;
        //      counted vmcnt at the tile boundary (never 0 in steady state) ----
        if (p2) { STAGE_Q(Bb + (T + 2) * 64, bC + 8192, 2);
                  STAGE_Q(Bb + (T + 2) * 64, bC + 8192, 3); }
        if (p2)      { asm volatile("s_waitcnt vmcnt(6)" ::: "memory"); }
        else if (p1) { asm volatile("s_waitcnt vmcnt(0)" ::: "memory"); }
        __builtin_amdgcn_s_barrier();
        __builtin_amdgcn_s_setprio(1);
        MFMA_Q(1, 0);
        __builtin_amdgcn_s_setprio(0);
        __builtin_amdgcn_sched_barrier(0);
        __builtin_amdgcn_s_barrier();
    }
#undef STAGE_Q
#undef LD_A
#undef LD_B
#undef MFMA_Q
#undef PH_SYNC_PRE
#undef PH_SYNC_POST
}

// ---------------- kernel 3: QKV GEMM (256x256 8-phase), M=Wc*196, N=2304 -----
// nblk 0..8: sec = nblk/3 (0=q,1=k,2=v). q,k -> [m][768]; v -> vt transposed.
// __launch_bounds__(512,1): LDS (128 KiB) already caps at 1 WG/CU; a (512,2)
// bound would impose a 256-VGPR cap -> spill into the counted-vmcnt region
// would corrupt the hand-counted vmcnt ledger (scratch ops enter vmcnt).
__global__ __launch_bounds__(512, 1) void gemm_qkv(const ushort* __restrict__ A,
                                                   const ushort* __restrict__ Wq,
                                                   const float* __restrict__ qkv_b,
                                                   ushort* __restrict__ qbuf,
                                                   ushort* __restrict__ kbuf,
                                                   ushort* __restrict__ vt,
                                                   int MB, int Wc) {
    __shared__ __align__(16) ushort sh[65536];       // 128 KiB
    const int tid = threadIdx.x, wave = tid >> 6, lane = tid & 63;
    const int quad = lane >> 4, l16 = lane & 15;
    const int wm = wave >> 2, wn = wave & 3;
    const int mblk = blockIdx.x % MB, nblk = blockIdx.x / MB;

    f32x4 acc[8][4];
    #pragma unroll
    for (int i = 0; i < 8; ++i)
        #pragma unroll
        for (int j = 0; j < 4; ++j) acc[i][j] = (f32x4){0.f, 0.f, 0.f, 0.f};

    kloop256(A + (size_t)mblk * 256 * 768, Wq + (size_t)nblk * 256 * 768, sh, acc);

    const int sec = nblk / 3;                        // block-uniform
    const int colq = nblk - sec * 3;
    #pragma unroll
    for (int nj = 0; nj < 4; ++nj) {
        const int col_in = colq * 256 + wn * 64 + nj * 16 + l16;   // 0..767
        const float bias = qkv_b[sec * 768 + col_in];
        #pragma unroll
        for (int mi = 0; mi < 8; ++mi) {
            #pragma unroll
            for (int r = 0; r < 4; ++r) {
                const int m = mblk * 256 + wm * 128 + mi * 16 + quad * 4 + r;
                const float v = acc[mi][nj][r] + bias;
                if (sec == 0) {
                    qbuf[(size_t)m * 768 + col_in] = f2h_u(v);
                } else if (sec == 1) {
                    kbuf[(size_t)m * 768 + col_in] = f2h_u(v);
                } else {
                    const int win = m / 196, tok = m - win * 196;
                    const int head = col_in >> 6, d = col_in & 63;
                    vt[((size_t)(head * Wc + win) * 64 + d) * 208 + tok] = f2h_u(v);
                }
            }
        }
    }
}

// ---------------- kernel 4: attention per (win, head), 4 waves ---------------
// k_s: two stride-32 halves (even bank spread); v_t padded to 216 (even spread).
__global__ __launch_bounds__(256) void attn(const ushort* __restrict__ qbuf,
                                            const ushort* __restrict__ kbuf,
                                            const ushort* __restrict__ vt,
                                            ushort* __restrict__ ow, int Wc) {
    __shared__ __align__(16) ushort k_s[2 * 208 * 32];   // 26,624 B
    __shared__ __align__(16) ushort v_t[64 * 216];       // 27,648 B
    __shared__ __align__(16) ushort pscr[4 * 512];       //  4,096 B
    const int tid = threadIdx.x, wave = tid >> 6, lane = tid & 63;
    const int quad = lane >> 4, l16 = lane & 15;
    const int head = blockIdx.x % NHEAD, win = blockIdx.x / NHEAD;

    // early q fragment loads (in flight behind staging + barrier)
    half8 aq0[4], aq1[4];
    #pragma unroll
    for (int si = 0; si < 4; ++si) {
        int strip = wave + si * 4; if (strip > 12) strip = 12;
        int qtok = strip * 16 + l16; if (qtok > 195) qtok = 195;
        const ushort* qp = qbuf + (size_t)(win * NTOK + qtok) * 768 + head * 64 + quad * 8;
        aq0[si] = *(const half8*)qp;
        aq1[si] = *(const half8*)(qp + 32);
    }

    // stage k (zero-pad rows >=196), split halves d<32 / d>=32
    for (int c = tid; c < 1664; c += 256) {
        const int row = c >> 3, c8 = c & 7;
        half8 val = {};
        if (row < NTOK)
            val = *(const half8*)(kbuf + (size_t)(win * NTOK + row) * 768 + head * 64 + c8 * 8);
        *(half8*)(k_s + ((c8 >> 2) * 208 + row) * 32 + (c8 & 3) * 8) = val;
    }
    // stage v_t (global vt already transposed; pad cols 196..207 are zeroed via memset)
    {
        const ushort* vsrc = vt + (size_t)(head * Wc + win) * 64 * 208;
        for (int c = tid; c < 1664; c += 256) {
            const int d = c / 26, c8 = c - d * 26;
            *(half8*)(v_t + d * 216 + c8 * 8) = *(const half8*)(vsrc + d * 208 + c8 * 8);
        }
    }
    __syncthreads();

    ushort* ps = pscr + wave * 512;
    for (int si = 0; si < 4; ++si) {
        const int strip = wave + si * 4;
        if (strip > 12) break;                        // wave-uniform
        // ---- S = q k^T ----
        f32x4 sacc[13];
        #pragma unroll
        for (int nt = 0; nt < 13; ++nt) sacc[nt] = (f32x4){0.f, 0.f, 0.f, 0.f};
        #pragma unroll
        for (int nt = 0; nt < 13; ++nt) {
            const int krow = (nt * 16 + l16) * 32 + quad * 8;
            half8 kb0 = *(const half8*)(k_s + krow);
            half8 kb1 = *(const half8*)(k_s + 208 * 32 + krow);
            sacc[nt] = __builtin_amdgcn_mfma_f32_16x16x32_f16(aq0[si], kb0, sacc[nt], 0, 0, 0);
            sacc[nt] = __builtin_amdgcn_mfma_f32_16x16x32_f16(aq1[si], kb1, sacc[nt], 0, 0, 0);
        }
        // ---- exact softmax per row (cols spread over l16) ----
        float P[13][4], linv[4];
        #pragma unroll
        for (int r = 0; r < 4; ++r) {
            float sv[13];
            float mx = -1e30f;
            #pragma unroll
            for (int nt = 0; nt < 13; ++nt) {
                float s = sacc[nt][r] * 0.125f;
                if (nt == 12 && l16 >= 4) s = -1e30f;   // mask cols >= 196
                sv[nt] = s;
                mx = fmaxf(mx, s);
            }
            mx = fmaxf(mx, __shfl_xor(mx, 1));
            mx = fmaxf(mx, __shfl_xor(mx, 2));
            mx = fmaxf(mx, __shfl_xor(mx, 4));
            mx = fmaxf(mx, __shfl_xor(mx, 8));
            float l = 0.f;
            #pragma unroll
            for (int nt = 0; nt < 13; ++nt) {
                float e = __expf(sv[nt] - mx);
                P[nt][r] = e;
                l += e;
            }
            l += __shfl_xor(l, 1);
            l += __shfl_xor(l, 2);
            l += __shfl_xor(l, 4);
            l += __shfl_xor(l, 8);
            linv[r] = 1.f / l;
        }
        // ---- O = P V ----
        f32x4 oacc[4];
        #pragma unroll
        for (int dt = 0; dt < 4; ++dt) oacc[dt] = (f32x4){0.f, 0.f, 0.f, 0.f};
        #pragma unroll
        for (int ks = 0; ks < 6; ++ks) {              // K=32 steps, tokens 0..191
            #pragma unroll
            for (int h = 0; h < 2; ++h) {
                const int nt = ks * 2 + h;
                #pragma unroll
                for (int r = 0; r < 4; ++r)
                    ps[(quad * 4 + r) * 32 + h * 16 + l16] = f2h_u(P[nt][r]);
            }
            half8 a = *(const half8*)(ps + l16 * 32 + quad * 8);
            #pragma unroll
            for (int dt = 0; dt < 4; ++dt) {
                half8 vb = *(const half8*)(v_t + (dt * 16 + l16) * 216 + ks * 32 + quad * 8);
                oacc[dt] = __builtin_amdgcn_mfma_f32_16x16x32_f16(a, vb, oacc[dt], 0, 0, 0);
            }
        }
        {                                             // final K=16, tokens 192..207
            #pragma unroll
            for (int r = 0; r < 4; ++r)
                ps[(quad * 4 + r) * 32 + l16] = f2h_u(P[12][r]);
            half4 a4 = *(const half4*)(ps + l16 * 32 + quad * 4);
            #pragma unroll
            for (int dt = 0; dt < 4; ++dt) {
                half4 vb4 = *(const half4*)(v_t + (dt * 16 + l16) * 216 + 192 + quad * 4);
                oacc[dt] = __builtin_amdgcn_mfma_f32_16x16x16f16(a4, vb4, oacc[dt], 0, 0, 0);
            }
        }
        // ---- store ----
        const int sb = strip * 16;
        #pragma unroll
        for (int r = 0; r < 4; ++r) {
            const int token = sb + quad * 4 + r;
            if (token < NTOK) {
                #pragma unroll
                for (int dt = 0; dt < 4; ++dt)
                    ow[(size_t)(win * NTOK + token) * 768 + head * 64 + dt * 16 + l16] =
                        f2h_u(oacc[dt][r] * linv[r]);
            }
        }
    }
}

// ---------------- kernel 5: proj GEMM (50176x768x768, 256x256 8-phase) ------
__global__ __launch_bounds__(512, 1) void proj_k(const ushort* __restrict__ ow,
                                                 const ushort* __restrict__ wp,
                                                 const float* __restrict__ pb,
                                                 float* __restrict__ out) {
    __shared__ __align__(16) ushort sh[65536];       // 128 KiB
    const int tid = threadIdx.x, wave = tid >> 6, lane = tid & 63;
    const int quad = lane >> 4, l16 = lane & 15;
    const int wm = wave >> 2, wn = wave & 3;
    const int mblk = blockIdx.x % 196, nblk = blockIdx.x / 196;

    f32x4 acc[8][4];
    #pragma unroll
    for (int i = 0; i < 8; ++i)
        #pragma unroll
        for (int j = 0; j < 4; ++j) acc[i][j] = (f32x4){0.f, 0.f, 0.f, 0.f};

    kloop256(ow + (size_t)mblk * 256 * 768, wp + (size_t)nblk * 256 * 768, sh, acc);

    #pragma unroll
    for (int mi = 0; mi < 8; ++mi) {
        #pragma unroll
        for (int r = 0; r < 4; ++r) {
            int grow = mblk * 256 + wm * 128 + mi * 16 + quad * 4 + r;   // < 50176
            int wnd = grow / 196, tok = grow - wnd * 196;
            int b = wnd >> 4, wh = (wnd >> 2) & 3, ww = wnd & 3;
            int rr = tok / 14, cc = tok - rr * 14;
            float* orow = out + ((b * 56 + wh * 14 + rr) * 56 + ww * 14 + cc) * 768;
            #pragma unroll
            for (int nj = 0; nj < 4; ++nj) {
                int col = nblk * 256 + wn * 64 + nj * 16 + l16;
                orow[col] = acc[mi][nj][r] + pb[col];
            }
        }
    }
}

extern "C" void kernel_launch(void* const* d_in, const int* in_sizes, int n_in,
                              void* d_out, int out_size, void* d_ws, size_t ws_size,
                              hipStream_t stream) {
    const float* x      = (const float*)d_in[0];
    const float* qkv_w  = (const float*)d_in[1];
    const float* qkv_b  = (const float*)d_in[2];
    const float* proj_w = (const float*)d_in[3];
    const float* proj_b = (const float*)d_in[4];
    float* out = (float*)d_out;

    char* ws = (char*)d_ws;
    ushort* xb = (ushort*)ws;                         // 77,070,336 B; later aliased as ow
    ushort* wq = (ushort*)(ws + 77070336);            //  3,538,944 B
    ushort* wp = (ushort*)(ws + 80609280);            //  1,179,648 B
    char* dyn = ws + 81788928;

    // chunk window count by available workspace (q + k + vt per window = 921,600 B)
    // Wc must be a multiple of 64 so Wc*196 % 256 == 0 (256-row GEMM tiles).
    size_t avail = ws_size > 81788928u ? ws_size - 81788928u : 0;
    int Wc = 256;
    while (Wc > 64 && (size_t)Wc * 921600u > avail) Wc >>= 1;
    const int nchunk = 256 / Wc;
    const int MB = Wc * NTOK / 256;                   // Wc mult of 64 -> exact

    ushort* qbuf = (ushort*)dyn;
    ushort* kbuf = qbuf + (size_t)Wc * NTOK * 768;
    ushort* vt   = kbuf + (size_t)Wc * NTOK * 768;

    cvt_x<<<37632, 256, 0, stream>>>(x, xb);
    cvt_w<<<2304, 256, 0, stream>>>(qkv_w, proj_w, wq, wp);
    hipMemsetAsync(vt, 0, (size_t)Wc * NHEAD * 64 * 208 * 2, stream);  // zero vt pad cols

    for (int c = 0; c < nchunk; ++c) {
        const ushort* xbc = xb + (size_t)c * Wc * NTOK * 768;
        ushort* owc = xb + (size_t)c * Wc * NTOK * 768;   // alias: chunk's xb dead after gemm
        gemm_qkv<<<MB * 9, 512, 0, stream>>>(xbc, wq, qkv_b, qbuf, kbuf, vt, MB, Wc);
        attn<<<Wc * NHEAD, 256, 0, stream>>>(qbuf, kbuf, vt, owc, Wc);
    }
    proj_k<<<196 * 3, 512, 0, stream>>>(xb, wp, proj_b, out);
}

// Round 3
// 755.893 us; speedup vs baseline: 1.2050x; 1.1786x over previous
//
#include <hip/hip_runtime.h>

typedef _Float16 half8 __attribute__((ext_vector_type(8)));
typedef _Float16 half4 __attribute__((ext_vector_type(4)));
typedef float f32x4 __attribute__((ext_vector_type(4)));

#define NTOK 196           // tokens per window (14*14)
#define NHEAD 12

__device__ __forceinline__ ushort f2h_u(float f) {
    _Float16 h = (_Float16)f;
    return __builtin_bit_cast(ushort, h);
}

// async 16B global->LDS. lds ptr must be wave-uniform base; HW adds lane*16.
__device__ __forceinline__ void gl_lds16(const ushort* g, ushort* l) {
    __builtin_amdgcn_global_load_lds((const __attribute__((address_space(1))) void*)g,
                                     (__attribute__((address_space(3))) void*)l,
                                     16, 0, 0);
}

// m204 bijective XCD-chunked bid remap: consecutive wg per XCD, any nwg.
__device__ __forceinline__ int xcd_swz(int bid, int nwg) {
    const int x = bid & 7, o = bid >> 3;
    const int qq = nwg >> 3, rr = nwg & 7;
    return (x < rr ? x * (qq + 1) : rr * (qq + 1) + (x - rr) * qq) + o;
}

// ---------------- kernel 1: gather x into window-token order, fp32 -> fp16 ----
__global__ __launch_bounds__(256) void cvt_x(const float* __restrict__ x,
                                             ushort* __restrict__ xb) {
    int idx = blockIdx.x * 256 + threadIdx.x;        // < 50176*192 exactly
    int t   = idx / 192;
    int c   = (idx - t * 192) * 4;
    int win = t / NTOK;
    int n   = t - win * NTOK;
    int b  = win >> 4, wh = (win >> 2) & 3, ww = win & 3;
    int r  = n / 14,  cc = n - r * 14;
    const float4 v = *(const float4*)(x + (((b * 56 + wh * 14 + r) * 56) + ww * 14 + cc) * 768 + c);
    ushort4 o = make_ushort4(f2h_u(v.x), f2h_u(v.y), f2h_u(v.z), f2h_u(v.w));
    *(ushort4*)(xb + t * 768 + c) = o;
}

// ---------------- kernel 2: weights fp32 -> fp16 -----------------------------
__global__ __launch_bounds__(256) void cvt_w(const float* __restrict__ qkv_w,
                                             const float* __restrict__ proj_w,
                                             ushort* __restrict__ wq,
                                             ushort* __restrict__ wp) {
    int idx = blockIdx.x * 256 + threadIdx.x;        // < 3072*192 exactly
    int row = idx / 192;
    int c   = (idx - row * 192) * 4;
    const float* src;
    ushort* dst;
    if (row < 2304) { src = qkv_w + row * 768 + c;          dst = wq + row * 768 + c; }
    else            { src = proj_w + (row - 2304) * 768 + c; dst = wp + (row - 2304) * 768 + c; }
    float4 v = *(const float4*)src;
    *(ushort4*)dst = make_ushort4(f2h_u(v.x), f2h_u(v.y), f2h_u(v.z), f2h_u(v.w));
}

// ============================================================================
// Shared 256x256xK(=768) 8-phase K-loop (T2 swizzle + T3/T4 counted vmcnt + T5)
// 8 waves (2M x 4N), BK=64, double-buffered 128 KiB LDS.
// LDS map (ushort idx): A: buf*16384 + half*8192 ; B: 32768 + same.
// Half = 128 rows x 64 k-halfs (128 B/row). Read swizzle byte ^= ((row&7)<<4),
// realized at write time by pre-swizzling the per-lane global source column
// (global_load_lds writes linearly: rule #21 both-sides-or-neither).
// vmcnt ledger (steady state): 2 issues/phase x 4 phases; vmcnt(6) at phase 4
// retires exactly through iter-T-phase-1 = all of tile T+1. Tail: T=NT-2
// drains vmcnt(0); T=NT-1 stages nothing. Zero outstanding at loop exit.
// ============================================================================
__device__ __forceinline__ void kloop256(const ushort* __restrict__ Ab,
                                         const ushort* __restrict__ Bb,
                                         ushort* sh,
                                         f32x4 (&acc)[8][4]) {
    const int tid = threadIdx.x, wave = tid >> 6, lane = tid & 63;
    const int quad = lane >> 4, l16 = lane & 15;
    const int wm = wave >> 2, wn = wave & 3;
    const int sr = lane >> 3;                       // 0..7 row-in-chunk
    const int sc = ((lane & 7) ^ sr) * 8;           // pre-swizzled col (halfs)
    const int rd_xor = (l16 & 7) << 4;              // read-side swizzle (bytes)
    const int rowB0 = (wn & 1) * 64;
    half8 Ar[4][2], Br[2][2][2];

    // stage one 64-row quarter (8 waves x 1 gl_lds = 8 KB). ldsHalf = half base.
#define STAGE_Q(srcK, ldsHalf, q) \
    gl_lds16((srcK) + ((q) * 64 + wave * 8 + sr) * 768 + sc, \
             (ldsHalf) + (((q) & 1) * 64 + wave * 8) * 64)

#define LD_A(QM, aB) \
    _Pragma("unroll") for (int mi = 0; mi < 4; ++mi) \
    _Pragma("unroll") for (int kk = 0; kk < 2; ++kk) \
        Ar[mi][kk] = *(const half8*)((aB) + \
            (((((QM) * 64 + mi * 16 + l16) * 128) + kk * 64 + quad * 16) ^ rd_xor))

#define LD_B(QN, bB) \
    _Pragma("unroll") for (int nj = 0; nj < 2; ++nj) \
    _Pragma("unroll") for (int kk = 0; kk < 2; ++kk) \
        Br[QN][nj][kk] = *(const half8*)((bB) + \
            ((((rowB0 + (QN) * 32 + nj * 16 + l16) * 128) + kk * 64 + quad * 16) ^ rd_xor))

#define MFMA_Q(QM, QN) \
    _Pragma("unroll") for (int mi = 0; mi < 4; ++mi) \
    _Pragma("unroll") for (int nj = 0; nj < 2; ++nj) \
    _Pragma("unroll") for (int kk = 0; kk < 2; ++kk) \
        acc[(QM) * 4 + mi][(QN) * 2 + nj] = __builtin_amdgcn_mfma_f32_16x16x32_f16( \
            Ar[mi][kk], Br[QN][nj][kk], acc[(QM) * 4 + mi][(QN) * 2 + nj], 0, 0, 0)

#define PH_SYNC_PRE() do { \
    __builtin_amdgcn_s_barrier(); \
    asm volatile("s_waitcnt lgkmcnt(0)" ::: "memory"); \
    __builtin_amdgcn_sched_barrier(0); \
    __builtin_amdgcn_s_setprio(1); } while (0)

#define PH_SYNC_POST() do { \
    __builtin_amdgcn_s_setprio(0); \
    __builtin_amdgcn_sched_barrier(0); \
    __builtin_amdgcn_s_barrier(); } while (0)

    // ---- prologue: tile0 fully; tile1 A_q0,A_q2 + B_q0..3 (6 loads last) ----
    {
        ushort* a0 = sh;
        ushort* b0 = sh + 32768;
        #pragma unroll
        for (int q = 0; q < 4; ++q) STAGE_Q(Ab, a0 + (q >> 1) * 8192, q);
        #pragma unroll
        for (int q = 0; q < 4; ++q) STAGE_Q(Bb, b0 + (q >> 1) * 8192, q);
        ushort* a1 = sh + 16384;
        ushort* b1 = sh + 32768 + 16384;
        STAGE_Q(Ab + 64, a1, 0);
        STAGE_Q(Ab + 64, a1 + 8192, 2);
        #pragma unroll
        for (int q = 0; q < 4; ++q) STAGE_Q(Bb + 64, b1 + (q >> 1) * 8192, q);
        asm volatile("s_waitcnt vmcnt(6)" ::: "memory");   // tile0 complete
        __builtin_amdgcn_s_barrier();
    }

    const int NT = 12;                               // K = 768 / 64
    for (int T = 0; T < NT; ++T) {
        const int buf = T & 1;
        const char* aB = (const char*)(sh + buf * 16384 + wm * 8192);
        const char* bB = (const char*)(sh + 32768 + buf * 16384 + (wn >> 1) * 8192);
        ushort* aN = sh + (buf ^ 1) * 16384;         // tile T+1 A buffer
        ushort* aC = sh + buf * 16384;               // tile T+2 buffers (== cur)
        ushort* bC = sh + 32768 + buf * 16384;
        const bool p1 = (T + 1 < NT), p2 = (T + 2 < NT);

        // ---- phase 1: Q(0,0); issue A_q1,A_q3 of T+1 ----
        LD_A(0, aB); LD_B(0, bB);
        if (p1) { STAGE_Q(Ab + (T + 1) * 64, aN, 1);
                  STAGE_Q(Ab + (T + 1) * 64, aN + 8192, 3); }
        PH_SYNC_PRE(); MFMA_Q(0, 0); PH_SYNC_POST();

        // ---- phase 2: Q(0,1); issue A_q0,A_q2 of T+2 (regions read @ph1) ----
        LD_B(1, bB);
        if (p2) { STAGE_Q(Ab + (T + 2) * 64, aC, 0);
                  STAGE_Q(Ab + (T + 2) * 64, aC + 8192, 2); }
        PH_SYNC_PRE(); MFMA_Q(0, 1); PH_SYNC_POST();

        // ---- phase 3: Q(1,1); issue B_q0,B_q1 of T+2 (B read done @ph2) ----
        LD_A(1, aB);
        if (p2) { STAGE_Q(Bb + (T + 2) * 64, bC, 0);
                  STAGE_Q(Bb + (T + 2) * 64, bC, 1); }
        PH_SYNC_PRE(); MFMA_Q(1, 1); PH_SYNC_POST();

        // ---- phase 4: Q(1,0) on retained regs; issue B_q2,B_q3 of T+2;
        //      counted vmcnt at the tile boundary (never 0 in steady state) ----
        if (p2) { STAGE_Q(Bb + (T + 2) * 64, bC + 8192, 2);
                  STAGE_Q(Bb + (T + 2) * 64, bC + 8192, 3); }
        if (p2)      { asm volatile("s_waitcnt vmcnt(6)" ::: "memory"); }
        else if (p1) { asm volatile("s_waitcnt vmcnt(0)" ::: "memory"); }
        __builtin_amdgcn_s_barrier();
        __builtin_amdgcn_s_setprio(1);
        MFMA_Q(1, 0);
        __builtin_amdgcn_s_setprio(0);
        __builtin_amdgcn_sched_barrier(0);
        __builtin_amdgcn_s_barrier();
    }
#undef STAGE_Q
#undef LD_A
#undef LD_B
#undef MFMA_Q
#undef PH_SYNC_PRE
#undef PH_SYNC_POST
}

// ---------------- kernel 3: QKV GEMM (256x256 8-phase), M=Wc*196, N=2304 -----
// wg order: nblk-inner (9 consecutive wgs share the A-panel -> in-L2 reuse),
// XCD-chunked bijective swizzle on top. sec = nblk/3 (0=q,1=k,2=v).
// v-sector epilogue goes through a transposed LDS tile -> coalesced 8B stores
// (old path: 2B stores at 416B lane stride -> RFO/partial-line poison).
__global__ __launch_bounds__(512, 1) void gemm_qkv(const ushort* __restrict__ A,
                                                   const ushort* __restrict__ Wq,
                                                   const float* __restrict__ qkv_b,
                                                   ushort* __restrict__ qbuf,
                                                   ushort* __restrict__ kbuf,
                                                   ushort* __restrict__ vt,
                                                   int MB, int Wc) {
    __shared__ __align__(16) ushort sh[65536];       // 128 KiB
    const int tid = threadIdx.x, wave = tid >> 6, lane = tid & 63;
    const int quad = lane >> 4, l16 = lane & 15;
    const int wm = wave >> 2, wn = wave & 3;
    const int wg = xcd_swz(blockIdx.x, MB * 9);
    const int mblk = wg / 9, nblk = wg - (wg / 9) * 9;

    f32x4 acc[8][4];
    #pragma unroll
    for (int i = 0; i < 8; ++i)
        #pragma unroll
        for (int j = 0; j < 4; ++j) acc[i][j] = (f32x4){0.f, 0.f, 0.f, 0.f};

    kloop256(A + (size_t)mblk * 256 * 768, Wq + (size_t)nblk * 256 * 768, sh, acc);

    const int sec = nblk / 3;                        // block-uniform
    const int colq = nblk - sec * 3;
    if (sec != 2) {
        // ---- q/k: direct stores (4-row x 32B chunks, adequate) ----
        #pragma unroll
        for (int nj = 0; nj < 4; ++nj) {
            const int col_in = colq * 256 + wn * 64 + nj * 16 + l16;   // 0..767
            const float bias = qkv_b[sec * 768 + col_in];
            ushort* dst = (sec == 0) ? qbuf : kbuf;
            #pragma unroll
            for (int mi = 0; mi < 8; ++mi) {
                #pragma unroll
                for (int r = 0; r < 4; ++r) {
                    const int m = mblk * 256 + wm * 128 + mi * 16 + quad * 4 + r;
                    dst[(size_t)m * 768 + col_in] = f2h_u(acc[mi][nj][r] + bias);
                }
            }
        }
    } else {
        // ---- v: transposed-LDS epilogue. Two 128-row passes.
        // LDS tile: [col 0..255][token-local 0..127], stride 132 (8B-aligned
        // 4-token chunks, ~2-way banks). Stores: 4-token uint2 runs (196%4==0
        // -> never cross a window); pad cols 196..207 stay memset-zero. ----
        const float* bv = qkv_b + 2 * 768;
        #pragma unroll
        for (int p = 0; p < 2; ++p) {
            __syncthreads();
            if (wm == p) {
                #pragma unroll
                for (int nj = 0; nj < 4; ++nj) {
                    const int col = wn * 64 + nj * 16 + l16;
                    const float bias = bv[colq * 256 + col];
                    #pragma unroll
                    for (int mi = 0; mi < 8; ++mi) {
                        #pragma unroll
                        for (int r = 0; r < 4; ++r)
                            sh[col * 132 + mi * 16 + quad * 4 + r] =
                                f2h_u(acc[mi][nj][r] + bias);
                    }
                }
            }
            __syncthreads();
            #pragma unroll
            for (int i = 0; i < 16; ++i) {
                const int ch = i * 512 + tid;        // 0..8191
                const int col = ch >> 5, tq = ch & 31;
                const int m = mblk * 256 + p * 128 + tq * 4;
                const int win = m / 196, tok = m - win * 196;
                const int cin = colq * 256 + col;
                const int head = cin >> 6, d = cin & 63;
                *(uint2*)(vt + ((size_t)(head * Wc + win) * 64 + d) * 208 + tok) =
                    *(const uint2*)(sh + col * 132 + tq * 4);
            }
        }
    }
}

// ---------------- kernel 4: attention per (win, head), 4 waves ---------------
// k_s: two stride-32 halves (even bank spread); v_t padded to 216 (even spread).
__global__ __launch_bounds__(256) void attn(const ushort* __restrict__ qbuf,
                                            const ushort* __restrict__ kbuf,
                                            const ushort* __restrict__ vt,
                                            ushort* __restrict__ ow, int Wc) {
    __shared__ __align__(16) ushort k_s[2 * 208 * 32];   // 26,624 B
    __shared__ __align__(16) ushort v_t[64 * 216];       // 27,648 B
    __shared__ __align__(16) ushort pscr[4 * 512];       //  4,096 B
    const int tid = threadIdx.x, wave = tid >> 6, lane = tid & 63;
    const int quad = lane >> 4, l16 = lane & 15;
    const int head = blockIdx.x % NHEAD, win = blockIdx.x / NHEAD;

    // early q fragment loads (in flight behind staging + barrier)
    half8 aq0[4], aq1[4];
    #pragma unroll
    for (int si = 0; si < 4; ++si) {
        int strip = wave + si * 4; if (strip > 12) strip = 12;
        int qtok = strip * 16 + l16; if (qtok > 195) qtok = 195;
        const ushort* qp = qbuf + (size_t)(win * NTOK + qtok) * 768 + head * 64 + quad * 8;
        aq0[si] = *(const half8*)qp;
        aq1[si] = *(const half8*)(qp + 32);
    }

    // stage k (zero-pad rows >=196), split halves d<32 / d>=32
    for (int c = tid; c < 1664; c += 256) {
        const int row = c >> 3, c8 = c & 7;
        half8 val = {};
        if (row < NTOK)
            val = *(const half8*)(kbuf + (size_t)(win * NTOK + row) * 768 + head * 64 + c8 * 8);
        *(half8*)(k_s + ((c8 >> 2) * 208 + row) * 32 + (c8 & 3) * 8) = val;
    }
    // stage v_t (global vt already transposed; pad cols 196..207 are zeroed via memset)
    {
        const ushort* vsrc = vt + (size_t)(head * Wc + win) * 64 * 208;
        for (int c = tid; c < 1664; c += 256) {
            const int d = c / 26, c8 = c - d * 26;
            *(half8*)(v_t + d * 216 + c8 * 8) = *(const half8*)(vsrc + d * 208 + c8 * 8);
        }
    }
    __syncthreads();

    ushort* ps = pscr + wave * 512;
    for (int si = 0; si < 4; ++si) {
        const int strip = wave + si * 4;
        if (strip > 12) break;                        // wave-uniform
        // ---- S = q k^T ----
        f32x4 sacc[13];
        #pragma unroll
        for (int nt = 0; nt < 13; ++nt) sacc[nt] = (f32x4){0.f, 0.f, 0.f, 0.f};
        #pragma unroll
        for (int nt = 0; nt < 13; ++nt) {
            const int krow = (nt * 16 + l16) * 32 + quad * 8;
            half8 kb0 = *(const half8*)(k_s + krow);
            half8 kb1 = *(const half8*)(k_s + 208 * 32 + krow);
            sacc[nt] = __builtin_amdgcn_mfma_f32_16x16x32_f16(aq0[si], kb0, sacc[nt], 0, 0, 0);
            sacc[nt] = __builtin_amdgcn_mfma_f32_16x16x32_f16(aq1[si], kb1, sacc[nt], 0, 0, 0);
        }
        // ---- exact softmax per row (cols spread over l16) ----
        float P[13][4], linv[4];
        #pragma unroll
        for (int r = 0; r < 4; ++r) {
            float sv[13];
            float mx = -1e30f;
            #pragma unroll
            for (int nt = 0; nt < 13; ++nt) {
                float s = sacc[nt][r] * 0.125f;
                if (nt == 12 && l16 >= 4) s = -1e30f;   // mask cols >= 196
                sv[nt] = s;
                mx = fmaxf(mx, s);
            }
            mx = fmaxf(mx, __shfl_xor(mx, 1));
            mx = fmaxf(mx, __shfl_xor(mx, 2));
            mx = fmaxf(mx, __shfl_xor(mx, 4));
            mx = fmaxf(mx, __shfl_xor(mx, 8));
            float l = 0.f;
            #pragma unroll
            for (int nt = 0; nt < 13; ++nt) {
                float e = __expf(sv[nt] - mx);
                P[nt][r] = e;
                l += e;
            }
            l += __shfl_xor(l, 1);
            l += __shfl_xor(l, 2);
            l += __shfl_xor(l, 4);
            l += __shfl_xor(l, 8);
            linv[r] = 1.f / l;
        }
        // ---- O = P V ----
        f32x4 oacc[4];
        #pragma unroll
        for (int dt = 0; dt < 4; ++dt) oacc[dt] = (f32x4){0.f, 0.f, 0.f, 0.f};
        #pragma unroll
        for (int ks = 0; ks < 6; ++ks) {              // K=32 steps, tokens 0..191
            #pragma unroll
            for (int h = 0; h < 2; ++h) {
                const int nt = ks * 2 + h;
                #pragma unroll
                for (int r = 0; r < 4; ++r)
                    ps[(quad * 4 + r) * 32 + h * 16 + l16] = f2h_u(P[nt][r]);
            }
            half8 a = *(const half8*)(ps + l16 * 32 + quad * 8);
            #pragma unroll
            for (int dt = 0; dt < 4; ++dt) {
                half8 vb = *(const half8*)(v_t + (dt * 16 + l16) * 216 + ks * 32 + quad * 8);
                oacc[dt] = __builtin_amdgcn_mfma_f32_16x16x32_f16(a, vb, oacc[dt], 0, 0, 0);
            }
        }
        {                                             // final K=16, tokens 192..207
            #pragma unroll
            for (int r = 0; r < 4; ++r)
                ps[(quad * 4 + r) * 32 + l16] = f2h_u(P[12][r]);
            half4 a4 = *(const half4*)(ps + l16 * 32 + quad * 4);
            #pragma unroll
            for (int dt = 0; dt < 4; ++dt) {
                half4 vb4 = *(const half4*)(v_t + (dt * 16 + l16) * 216 + 192 + quad * 4);
                oacc[dt] = __builtin_amdgcn_mfma_f32_16x16x16f16(a4, vb4, oacc[dt], 0, 0, 0);
            }
        }
        // ---- store ----
        const int sb = strip * 16;
        #pragma unroll
        for (int r = 0; r < 4; ++r) {
            const int token = sb + quad * 4 + r;
            if (token < NTOK) {
                #pragma unroll
                for (int dt = 0; dt < 4; ++dt)
                    ow[(size_t)(win * NTOK + token) * 768 + head * 64 + dt * 16 + l16] =
                        f2h_u(oacc[dt][r] * linv[r]);
            }
        }
    }
}

// ---------------- kernel 5: proj GEMM (50176x768x768, 256x256 8-phase) ------
// wg order: nblk-inner (3 consecutive wgs share the A-panel), XCD-chunked.
__global__ __launch_bounds__(512, 1) void proj_k(const ushort* __restrict__ ow,
                                                 const ushort* __restrict__ wp,
                                                 const float* __restrict__ pb,
                                                 float* __restrict__ out) {
    __shared__ __align__(16) ushort sh[65536];       // 128 KiB
    const int tid = threadIdx.x, wave = tid >> 6, lane = tid & 63;
    const int quad = lane >> 4, l16 = lane & 15;
    const int wm = wave >> 2, wn = wave & 3;
    const int wg = xcd_swz(blockIdx.x, 196 * 3);
    const int mblk = wg / 3, nblk = wg - (wg / 3) * 3;

    f32x4 acc[8][4];
    #pragma unroll
    for (int i = 0; i < 8; ++i)
        #pragma unroll
        for (int j = 0; j < 4; ++j) acc[i][j] = (f32x4){0.f, 0.f, 0.f, 0.f};

    kloop256(ow + (size_t)mblk * 256 * 768, wp + (size_t)nblk * 256 * 768, sh, acc);

    #pragma unroll
    for (int mi = 0; mi < 8; ++mi) {
        #pragma unroll
        for (int r = 0; r < 4; ++r) {
            int grow = mblk * 256 + wm * 128 + mi * 16 + quad * 4 + r;   // < 50176
            int wnd = grow / 196, tok = grow - wnd * 196;
            int b = wnd >> 4, wh = (wnd >> 2) & 3, ww = wnd & 3;
            int rr = tok / 14, cc = tok - rr * 14;
            float* orow = out + ((b * 56 + wh * 14 + rr) * 56 + ww * 14 + cc) * 768;
            #pragma unroll
            for (int nj = 0; nj < 4; ++nj) {
                int col = nblk * 256 + wn * 64 + nj * 16 + l16;
                orow[col] = acc[mi][nj][r] + pb[col];
            }
        }
    }
}

extern "C" void kernel_launch(void* const* d_in, const int* in_sizes, int n_in,
                              void* d_out, int out_size, void* d_ws, size_t ws_size,
                              hipStream_t stream) {
    const float* x      = (const float*)d_in[0];
    const float* qkv_w  = (const float*)d_in[1];
    const float* qkv_b  = (const float*)d_in[2];
    const float* proj_w = (const float*)d_in[3];
    const float* proj_b = (const float*)d_in[4];
    float* out = (float*)d_out;

    char* ws = (char*)d_ws;
    ushort* xb = (ushort*)ws;                         // 77,070,336 B; later aliased as ow
    ushort* wq = (ushort*)(ws + 77070336);            //  3,538,944 B
    ushort* wp = (ushort*)(ws + 80609280);            //  1,179,648 B
    char* dyn = ws + 81788928;

    // chunk window count by available workspace (q + k + vt per window = 921,600 B)
    // Wc must be a multiple of 64 so Wc*196 % 256 == 0 (256-row GEMM tiles).
    size_t avail = ws_size > 81788928u ? ws_size - 81788928u : 0;
    int Wc = 256;
    while (Wc > 64 && (size_t)Wc * 921600u > avail) Wc >>= 1;
    const int nchunk = 256 / Wc;
    const int MB = Wc * NTOK / 256;                   // Wc mult of 64 -> exact

    ushort* qbuf = (ushort*)dyn;
    ushort* kbuf = qbuf + (size_t)Wc * NTOK * 768;
    ushort* vt   = kbuf + (size_t)Wc * NTOK * 768;

    cvt_x<<<37632, 256, 0, stream>>>(x, xb);
    cvt_w<<<2304, 256, 0, stream>>>(qkv_w, proj_w, wq, wp);
    hipMemsetAsync(vt, 0, (size_t)Wc * NHEAD * 64 * 208 * 2, stream);  // zero vt pad cols

    for (int c = 0; c < nchunk; ++c) {
        const ushort* xbc = xb + (size_t)c * Wc * NTOK * 768;
        ushort* owc = xb + (size_t)c * Wc * NTOK * 768;   // alias: chunk's xb dead after gemm
        gemm_qkv<<<MB * 9, 512, 0, stream>>>(xbc, wq, qkv_b, qbuf, kbuf, vt, MB, Wc);
        attn<<<Wc * NHEAD, 256, 0, stream>>>(qbuf, kbuf, vt, owc, Wc);
    }
    proj_k<<<196 * 3, 512, 0, stream>>>(xb, wp, proj_b, out);
}